// Round 1
// 1339.646 us; speedup vs baseline: 1.0049x; 1.0049x over previous
//
#include <hip/hip_runtime.h>
#include <math.h>

#define NUM_HEADS 32
#define HEAD_DIM 128
#define QRANK 1536
#define BSZ 8
#define SEQ 4096

// ---------------------------------------------------------------------------
// Fused kernel: one block per (b, h), 1024 threads = 16 waves.
//
// Phase 1 (qproj): q[b, h*128 .. h*128+127] = hidden[b,:] @ W[:, slice] + bias.
//   W slice = 768 KB; the 8 blocks sharing h sit on the same XCD (blockIdx%8
//   == h%8 under round-robin) -> L2 reuse; HBM cost of W ~= 24 MB total.
//
// Phase 2 (attn, single pass): for row r, K|V is one contiguous 1024 B chunk:
//   lanes 0..31 load K (ch 4*lane..), lanes 32..63 load V. Score = reduce of
//   q.K over lower half (5x shfl_xor + 1 broadcast). Online softmax
//   (branchless rescale) accumulates p*V on the upper half. One wave owns 256
//   rows. Per-wave (m, l, acc) combined across 16 waves via LDS at the end.
// ---------------------------------------------------------------------------
__global__ __launch_bounds__(1024) void fused_attn_kernel(
    const float* __restrict__ hq,   // [8][1536]
    const float* __restrict__ kv,   // [8][4096][32][256]  (K | V per row)
    const float* __restrict__ Wq,   // [1536][4096]
    const float* __restrict__ bq,   // [4096]
    float* __restrict__ out)        // [8][4096]
{
    __shared__ float  hs[QRANK];        // 6 KB   hidden row
    __shared__ float  qred[8][128];     // 4 KB   qproj partials
    __shared__ float  qs[HEAD_DIM];     // 512 B  q slice for this head
    __shared__ float4 ow[16][32];       // 8 KB   per-wave O partials
    __shared__ float  wm[16], wl[16];

    const int b    = blockIdx.x >> 5;   // 0..7
    const int h    = blockIdx.x & 31;   // 0..31
    const int tid  = threadIdx.x;
    const int w    = tid >> 6;          // wave 0..15
    const int lane = tid & 63;
    const int sub  = lane & 31;

    // ---- phase 1a: stage hidden[b,:] ----
    for (int i = tid; i < QRANK; i += 1024) hs[i] = hq[b * QRANK + i];
    __syncthreads();

    // ---- phase 1b: q projection, 8-way k-split ----
    {
        const int c  = tid & 127;       // column within head slice
        const int ks = tid >> 7;        // k-slice 0..7 (wave-uniform)
        const float* wp = Wq + (size_t)(ks * 192) * 4096 + h * 128 + c;
        float a = 0.f;
        #pragma unroll 4
        for (int k = 0; k < 192; ++k) {
            a += hs[ks * 192 + k] * wp[(size_t)k * 4096];
        }
        qred[ks][c] = a;
    }
    __syncthreads();
    if (tid < 128) {
        float s = bq[h * 128 + tid];
        #pragma unroll
        for (int i = 0; i < 8; ++i) s += qred[i][tid];
        qs[tid] = s;
    }
    __syncthreads();

    // ---- phase 2: single-pass online-softmax attention ----
    // Both halves read the same q fragment (upper half's dot is unused).
    const float4 qf = *(const float4*)(qs + 4 * sub);

    const float4* kv4 = (const float4*)kv;
    // float4 index of row r for this (b,h): ((b*SEQ + r)*2048) + h*64 + lane
    const size_t base = ((size_t)b * SEQ + (size_t)w * 256) * 2048
                      + (size_t)h * 64 + lane;

    float  m = -INFINITY;
    float  l = 0.f;
    float4 acc = make_float4(0.f, 0.f, 0.f, 0.f);

    #pragma unroll 4
    for (int r = 0; r < 256; ++r) {
        const float4 f = kv4[base + (size_t)r * 2048];
        // partial dot: meaningful on lanes 0..31 (K half)
        float p = qf.x * f.x + qf.y * f.y + qf.z * f.z + qf.w * f.w;
        p += __shfl_xor(p, 1);
        p += __shfl_xor(p, 2);
        p += __shfl_xor(p, 4);
        p += __shfl_xor(p, 8);
        p += __shfl_xor(p, 16);
        const float s = __shfl(p, 0);   // score, broadcast to all 64 lanes

        // branchless online-softmax update (state meaningful on upper half)
        const float mn = fmaxf(m, s);
        const float cs = __expf(m - mn);   // rescale (==1 almost always)
        const float pe = __expf(s - mn);
        l = l * cs + pe;
        acc.x = acc.x * cs + pe * f.x;
        acc.y = acc.y * cs + pe * f.y;
        acc.z = acc.z * cs + pe * f.z;
        acc.w = acc.w * cs + pe * f.w;
        m = mn;
    }

    if (lane >= 32) {
        if (lane == 32) { wm[w] = m; wl[w] = l; }
        ow[w][sub] = acc;               // channels 4*sub .. 4*sub+3
    }
    __syncthreads();

    // ---- combine 16 wave-partials, scale, store ----
    if (tid < 128) {
        float M = wm[0];
        #pragma unroll
        for (int i = 1; i < 16; ++i) M = fmaxf(M, wm[i]);
        float lt = 0.f;
        float s  = 0.f;
        #pragma unroll
        for (int i = 0; i < 16; ++i) {
            const float sc = __expf(wm[i] - M);
            lt += wl[i] * sc;
            const float* of = (const float*)(&ow[i][0]);   // [128] floats
            s += of[tid] * sc;
        }
        out[(size_t)b * 4096 + h * 128 + tid] = s / lt;
    }
}

extern "C" void kernel_launch(void* const* d_in, const int* in_sizes, int n_in,
                              void* d_out, int out_size, void* d_ws, size_t ws_size,
                              hipStream_t stream) {
    const float* hq = (const float*)d_in[0];   // [8][1536]
    const float* kv = (const float*)d_in[1];   // [8][4096][32][256]
    const float* Wq = (const float*)d_in[2];   // [1536][4096]
    const float* bq = (const float*)d_in[3];   // [4096]
    float* outp = (float*)d_out;               // [8][4096]
    (void)d_ws; (void)ws_size;

    fused_attn_kernel<<<BSZ * NUM_HEADS, 1024, 0, stream>>>(hq, kv, Wq, bq, outp);
}